// Round 14
// baseline (245.746 us; speedup 1.0000x reference)
//
#include <hip/hip_runtime.h>

typedef __attribute__((ext_vector_type(8))) short bf16x8;
typedef __attribute__((ext_vector_type(8))) unsigned short u16x8;
typedef __attribute__((ext_vector_type(4))) float f32x4;
typedef __attribute__((ext_vector_type(16))) float f32x16;
typedef __attribute__((ext_vector_type(4))) unsigned short u16x4;
typedef __attribute__((ext_vector_type(4))) unsigned int u32x4;
typedef unsigned int u32;

#define BB 2
#define LL 2048
#define DD 2048
#define HH 16
#define HDIM 128
#define MM 4096      // B*L
#define NQKV 6144    // 3*D

__device__ __forceinline__ unsigned short f2bf(float f) {
    unsigned int u = __builtin_bit_cast(unsigned int, f);
    u += 0x7FFFu + ((u >> 16) & 1u);
    return (unsigned short)(u >> 16);
}
__device__ __forceinline__ float bf2f(unsigned short h) {
    unsigned int u = ((unsigned int)h) << 16;
    return __builtin_bit_cast(float, u);
}

__device__ __forceinline__ void gload16(const unsigned short* g, unsigned short* l) {
    __builtin_amdgcn_global_load_lds((const __attribute__((address_space(1))) void*)g,
                                     (__attribute__((address_space(3))) void*)l, 16, 0, 0);
}

// packed f32->bf16 (RNE) and cross-half lane swap, for in-register softmax
__device__ __forceinline__ u32 cvtpk(float lo, float hi) {
    u32 r;
    asm("v_cvt_pk_bf16_f32 %0, %1, %2" : "=v"(r) : "v"(lo), "v"(hi));
    return r;
}
__device__ __forceinline__ void plswap(u32& a, u32& b) {
    asm("v_permlane32_swap_b32 %0, %1" : "+v"(a), "+v"(b));
}

// ============ merged prep: cvt x -> bf16 | transpose-convert wqkv, wout | rope table ============
__global__ __launch_bounds__(256) void k_prep(const float* __restrict__ x, unsigned short* __restrict__ xb,
                                              const float* __restrict__ wqkv, unsigned short* __restrict__ wqkvT,
                                              const float* __restrict__ wout, unsigned short* __restrict__ woutT,
                                              float* __restrict__ ct, float* __restrict__ st) {
    __shared__ unsigned short t[64][72];
    int bid = blockIdx.x;
    int tid = threadIdx.x;
    if (bid < 8192) {
        int i = bid * 256 + tid;
        float4 v = reinterpret_cast<const float4*>(x)[i];
        u16x4 o;
        o[0] = f2bf(v.x); o[1] = f2bf(v.y); o[2] = f2bf(v.z); o[3] = f2bf(v.w);
        reinterpret_cast<u16x4*>(xb)[i] = o;
        return;
    }
    if (bid >= 12288) {
        int idx = (bid - 12288) * 256 + tid;
        int pos = idx >> 6, d = idx & 63;
        float freq = __expf(-(float)d * (9.210340371976184f / 64.0f));
        float ang = (float)pos * freq;
        ct[idx] = cosf(ang);
        st[idx] = sinf(ang);
        return;
    }
    const float* in; unsigned short* out; int K, N, n0, k0;
    if (bid < 11264) {
        int r = bid - 8192;
        in = wqkv; out = wqkvT; K = DD; N = NQKV;
        n0 = (r % 96) * 64; k0 = (r / 96) * 64;
    } else {
        int r = bid - 11264;
        in = wout; out = woutT; K = DD; N = DD;
        n0 = (r & 31) * 64; k0 = (r >> 5) * 64;
    }
    int tr = tid >> 4, tc = tid & 15;
    #pragma unroll
    for (int i = 0; i < 4; ++i) {
        int k = i * 16 + tr;
        float4 v = *reinterpret_cast<const float4*>(in + (size_t)(k0 + k) * N + n0 + tc * 4);
        t[tc * 4 + 0][k] = f2bf(v.x);
        t[tc * 4 + 1][k] = f2bf(v.y);
        t[tc * 4 + 2][k] = f2bf(v.z);
        t[tc * 4 + 3][k] = f2bf(v.w);
    }
    __syncthreads();
    #pragma unroll
    for (int i = 0; i < 4; ++i) {
        int n = i * 16 + tr;
        u16x4 o = *reinterpret_cast<u16x4*>(&t[n][tc * 4]);
        *reinterpret_cast<u16x4*>(out + (size_t)(n0 + n) * K + k0 + tc * 4) = o;
    }
}

// ============ RoPE on K (vectorized, in place) ============
__global__ __launch_bounds__(256) void k_ropek(unsigned short* __restrict__ K,
                                               const float* __restrict__ ct,
                                               const float* __restrict__ st) {
    int idx = blockIdx.x * 256 + threadIdx.x;     // BB*HH*LL*8 = 524288
    int d0 = (idx & 7) * 8;
    int pos = (idx >> 3) & (LL - 1);
    int bh = idx >> 14;
    size_t base = ((size_t)bh * LL + pos) * HDIM;
    u16x8 k0 = *reinterpret_cast<const u16x8*>(K + base + d0);
    u16x8 k1 = *reinterpret_cast<const u16x8*>(K + base + 64 + d0);
    u16x8 o0, o1;
    #pragma unroll
    for (int j = 0; j < 8; ++j) {
        float c = ct[pos * 64 + d0 + j], s = st[pos * 64 + d0 + j];
        float a = bf2f(k0[j]), b = bf2f(k1[j]);
        o0[j] = f2bf(a * c - b * s);
        o1[j] = f2bf(b * c + a * s);
    }
    *reinterpret_cast<u16x8*>(K + base + d0) = o0;
    *reinterpret_cast<u16x8*>(K + base + 64 + d0) = o1;
}

// ============ GEMM1 (R12-proven body): 256x384, grid=256, BK=32, 4 LDS bufs, depth-3 ============
// V is written directly in transposed [bh][d][L] layout (outVt), killing the transV pass.
__global__ __launch_bounds__(512, 2) void k_gemm384(const unsigned short* __restrict__ A,
                                                    const unsigned short* __restrict__ Bt,
                                                    unsigned short* __restrict__ outQ,
                                                    unsigned short* __restrict__ outK,
                                                    unsigned short* __restrict__ outVt) {
    __shared__ unsigned short sm[4 * 20480];   // 160 KB exactly (1 block/CU)
    const int Kn = DD;
    const int tid = threadIdx.x;
    const int lane = tid & 63, w = tid >> 6;
    const int wm = w >> 2, wn = w & 3;
    const int lrow = lane & 15, lgrp = lane >> 4;
    const int NT = Kn / 32;

    int orig = blockIdx.x;
    int tau = (orig & 7) * 32 + (orig >> 3);
    const int m0 = (tau & 15) * 256, n0 = (tau >> 4) * 384;

    const int srow = lane >> 2, scol = lane & 3;
    const int scolg = ((scol ^ ((srow >> 1) & 3)) * 8);
    const int fcol  = ((lgrp ^ ((lrow >> 1) & 3)) * 8);

    f32x4 acc[8][6] = {};

    auto stageA = [&](int t, int r) {
        unsigned short* dst = sm + (t & 3) * 20480 + (r * 128 + w * 16) * 32;
        gload16(A + (size_t)(m0 + r * 128 + w * 16 + srow) * Kn + t * 32 + scolg, dst);
    };
    auto stageB = [&](int t, int r) {
        unsigned short* dst = sm + (t & 3) * 20480 + 8192 + (r * 128 + w * 16) * 32;
        gload16(Bt + (size_t)(n0 + r * 128 + w * 16 + srow) * Kn + t * 32 + scolg, dst);
    };

    auto body = [&](int t, bool doStage) {
        unsigned short* bufA = sm + (t & 3) * 20480;
        unsigned short* bufB = bufA + 8192;
        bf16x8 af[8], bfr[2];
        #pragma unroll
        for (int f = 0; f < 8; ++f)
            af[f] = *reinterpret_cast<const bf16x8*>(bufA + (wm * 128 + f * 16 + lrow) * 32 + fcol);
        bfr[0] = *reinterpret_cast<const bf16x8*>(bufB + (wn * 96 + 0 * 16 + lrow) * 32 + fcol);
        bfr[1] = *reinterpret_cast<const bf16x8*>(bufB + (wn * 96 + 1 * 16 + lrow) * 32 + fcol);
        if (doStage) { stageA(t + 3, 0); stageA(t + 3, 1); }
        __builtin_amdgcn_s_barrier();
        __builtin_amdgcn_s_setprio(1);
        #pragma unroll
        for (int fm = 0; fm < 8; ++fm)
            #pragma unroll
            for (int j = 0; j < 2; ++j)
                acc[fm][j] = __builtin_amdgcn_mfma_f32_16x16x32_bf16(af[fm], bfr[j], acc[fm][j], 0, 0, 0);
        __builtin_amdgcn_s_setprio(0);
        bfr[0] = *reinterpret_cast<const bf16x8*>(bufB + (wn * 96 + 2 * 16 + lrow) * 32 + fcol);
        bfr[1] = *reinterpret_cast<const bf16x8*>(bufB + (wn * 96 + 3 * 16 + lrow) * 32 + fcol);
        if (doStage) { stageB(t + 3, 0); stageB(t + 3, 1); }
        __builtin_amdgcn_s_barrier();
        __builtin_amdgcn_s_setprio(1);
        #pragma unroll
        for (int fm = 0; fm < 8; ++fm)
            #pragma unroll
            for (int j = 0; j < 2; ++j)
                acc[fm][2 + j] = __builtin_amdgcn_mfma_f32_16x16x32_bf16(af[fm], bfr[j], acc[fm][2 + j], 0, 0, 0);
        __builtin_amdgcn_s_setprio(0);
        bfr[0] = *reinterpret_cast<const bf16x8*>(bufB + (wn * 96 + 4 * 16 + lrow) * 32 + fcol);
        bfr[1] = *reinterpret_cast<const bf16x8*>(bufB + (wn * 96 + 5 * 16 + lrow) * 32 + fcol);
        if (doStage) { stageB(t + 3, 2); }
        __builtin_amdgcn_s_barrier();
        __builtin_amdgcn_s_setprio(1);
        #pragma unroll
        for (int fm = 0; fm < 8; ++fm)
            #pragma unroll
            for (int j = 0; j < 2; ++j)
                acc[fm][4 + j] = __builtin_amdgcn_mfma_f32_16x16x32_bf16(af[fm], bfr[j], acc[fm][4 + j], 0, 0, 0);
        __builtin_amdgcn_s_setprio(0);
    };

    stageA(0, 0); stageA(0, 1); stageB(0, 0); stageB(0, 1); stageB(0, 2);
    stageA(1, 0); stageA(1, 1); stageB(1, 0); stageB(1, 1); stageB(1, 2);
    stageA(2, 0); stageA(2, 1); stageB(2, 0); stageB(2, 1); stageB(2, 2);
    asm volatile("s_waitcnt vmcnt(10)" ::: "memory");
    __builtin_amdgcn_s_barrier();

    for (int t = 0; t < NT - 3; ++t) {
        body(t, true);
        asm volatile("s_waitcnt vmcnt(10)" ::: "memory");
        __builtin_amdgcn_s_barrier();
    }
    body(NT - 3, false);
    asm volatile("s_waitcnt vmcnt(5)" ::: "memory");
    __builtin_amdgcn_s_barrier();
    body(NT - 2, false);
    asm volatile("s_waitcnt vmcnt(0)" ::: "memory");
    __builtin_amdgcn_s_barrier();
    body(NT - 1, false);

    // epilogue: C row = lgrp*4 + i, col = lrow. Q/K scalar scatter; V packed u16x4 to [bh][d][L].
    #pragma unroll
    for (int fm = 0; fm < 8; ++fm) {
        int mrow = m0 + wm * 128 + fm * 16 + lgrp * 4;
        int b = mrow >> 11, pos = mrow & (LL - 1);   // mrow%4==0: b,pos stable across i
        #pragma unroll
        for (int fn = 0; fn < 6; ++fn) {
            int ncol = n0 + wn * 96 + fn * 16 + lrow;
            int which = ncol >> 11;
            int rr = ncol & (DD - 1);
            int h = rr >> 7, d = rr & (HDIM - 1);
            if (which == 2) {
                u16x4 o;
                #pragma unroll
                for (int i = 0; i < 4; ++i) o[i] = f2bf(acc[fm][fn][i]);
                *reinterpret_cast<u16x4*>(outVt + ((size_t)(b * HH + h) * HDIM + d) * LL + pos) = o;
            } else {
                unsigned short* dst = which ? outK : outQ;
                #pragma unroll
                for (int i = 0; i < 4; ++i)
                    dst[((size_t)(b * HH + h) * LL + pos + i) * HDIM + d] = f2bf(acc[fm][fn][i]);
            }
        }
    }
}

// ============ GEMM2: 256x128 tile, 8 waves, grid=256, 3 LDS bufs (2 blocks/CU) ============
__global__ __launch_bounds__(512) void k_gemm2x(const unsigned short* __restrict__ A,
                                                const unsigned short* __restrict__ Bt,
                                                float* __restrict__ outC) {
    __shared__ unsigned short sm[3 * 12288];
    const int Kn = DD, Nn = DD;
    const int tid = threadIdx.x;
    const int lane = tid & 63, w = tid >> 6;
    const int wm = w >> 1, wn = w & 1;
    const int lrow = lane & 15, lgrp = lane >> 4;
    const int NT = Kn / 32;

    int orig = blockIdx.x;
    int tau = (orig & 7) * 32 + (orig >> 3);
    const int m0 = (tau & 15) * 256, n0 = (tau >> 4) * 128;

    const int srow = lane >> 2, scol = lane & 3;
    const int scolg = ((scol ^ ((srow >> 1) & 3)) * 8);
    const int fcol  = ((lgrp ^ ((lrow >> 1) & 3)) * 8);

    f32x4 acc[4][4] = {};

    auto stage = [&](int t) {
        const int kb = t * 32;
        unsigned short* buf = sm + (t % 3) * 12288;
        gload16(A  + (size_t)(m0 + w * 16 + srow) * Kn + kb + scolg,        buf + w * 512);
        gload16(A  + (size_t)(m0 + 128 + w * 16 + srow) * Kn + kb + scolg,  buf + 4096 + w * 512);
        gload16(Bt + (size_t)(n0 + w * 16 + srow) * Kn + kb + scolg,        buf + 8192 + w * 512);
    };

    auto tile_body = [&](int t, bool do_stage) {
        unsigned short* buf = sm + (t % 3) * 12288;
        bf16x8 af[4], bfr[4];
        #pragma unroll
        for (int f = 0; f < 4; ++f)
            af[f] = *reinterpret_cast<const bf16x8*>(buf + (wm * 64 + f * 16 + lrow) * 32 + fcol);
        #pragma unroll
        for (int f = 0; f < 4; ++f)
            bfr[f] = *reinterpret_cast<const bf16x8*>(buf + 8192 + (wn * 64 + f * 16 + lrow) * 32 + fcol);
        if (do_stage) stage(t + 2);
        __builtin_amdgcn_s_barrier();
        __builtin_amdgcn_s_setprio(1);
        #pragma unroll
        for (int fm = 0; fm < 4; ++fm)
            #pragma unroll
            for (int fn = 0; fn < 4; ++fn)
                acc[fm][fn] = __builtin_amdgcn_mfma_f32_16x16x32_bf16(af[fm], bfr[fn], acc[fm][fn], 0, 0, 0);
        __builtin_amdgcn_s_setprio(0);
    };

    stage(0); stage(1);
    asm volatile("s_waitcnt vmcnt(3)" ::: "memory");
    __builtin_amdgcn_s_barrier();

    for (int t = 0; t < NT - 2; ++t) {
        tile_body(t, true);
        asm volatile("s_waitcnt vmcnt(3)" ::: "memory");
        __builtin_amdgcn_s_barrier();
    }
    tile_body(NT - 2, false);
    asm volatile("s_waitcnt vmcnt(0)" ::: "memory");
    __builtin_amdgcn_s_barrier();
    tile_body(NT - 1, false);

    #pragma unroll
    for (int fm = 0; fm < 4; ++fm) {
        int mrow = m0 + wm * 64 + fm * 16 + lgrp * 4;
        #pragma unroll
        for (int fn = 0; fn < 4; ++fn) {
            int ncol = n0 + wn * 64 + fn * 16 + lrow;
            #pragma unroll
            for (int i = 0; i < 4; ++i)
                outC[(size_t)(mrow + i) * (size_t)Nn + ncol] = acc[fm][fn][i];
        }
    }
}

// ============ attention (R9-proven): 4 waves, 32x32 MFMA, swapped QK^T, in-reg softmax, ============
// ============ dbuf, fused Q-RoPE. 180-VGPR live state => 2 waves/SIMD is the max here. ============
__global__ __launch_bounds__(256, 2) void k_attn(const unsigned short* __restrict__ Q,
                                                 const unsigned short* __restrict__ K,
                                                 const unsigned short* __restrict__ Vt,
                                                 unsigned short* __restrict__ Y,
                                                 const float* __restrict__ ct,
                                                 const float* __restrict__ st) {
    __shared__ unsigned short Kl[2][64][136];
    __shared__ unsigned short VTl[2][128][72];
    int tid = threadIdx.x;
    int lane = tid & 63, w = tid >> 6;
    int l31 = lane & 31, hl = lane >> 5;
    int orig = blockIdx.x;
    int id = (orig & 7) * 64 + (orig >> 3);
    int bh = id >> 4, qt = id & 15;
    int b = bh >> 4, hh = bh & 15;
    const unsigned short* Qb = Q  + (size_t)bh * LL * HDIM;
    const unsigned short* Kb = K  + (size_t)bh * LL * HDIM;
    const unsigned short* Vb = Vt + (size_t)bh * HDIM * LL;
    int q0 = qt * 128 + w * 32;

    bf16x8 qf[8];
    #pragma unroll
    for (int kk = 0; kk < 8; ++kk)
        qf[kk] = *reinterpret_cast<const bf16x8*>(
            Qb + (size_t)(q0 + l31) * HDIM + kk * 16 + hl * 8);
    // fused RoPE on Q: pair (d, d+64) = (qf[kk][j], qf[kk+4][j]) for kk<4
    {
        int pos = q0 + l31;
        #pragma unroll
        for (int kk = 0; kk < 4; ++kk) {
            int d0 = kk * 16 + hl * 8;
            float4 c0 = *reinterpret_cast<const float4*>(ct + pos * 64 + d0);
            float4 c1 = *reinterpret_cast<const float4*>(ct + pos * 64 + d0 + 4);
            float4 s0 = *reinterpret_cast<const float4*>(st + pos * 64 + d0);
            float4 s1 = *reinterpret_cast<const float4*>(st + pos * 64 + d0 + 4);
            float cs[8] = {c0.x, c0.y, c0.z, c0.w, c1.x, c1.y, c1.z, c1.w};
            float sn[8] = {s0.x, s0.y, s0.z, s0.w, s1.x, s1.y, s1.z, s1.w};
            #pragma unroll
            for (int j = 0; j < 8; ++j) {
                float a = bf2f((unsigned short)qf[kk][j]);
                float bb2 = bf2f((unsigned short)qf[kk + 4][j]);
                qf[kk][j]     = (short)f2bf(a * cs[j] - bb2 * sn[j]);
                qf[kk + 4][j] = (short)f2bf(bb2 * cs[j] + a * sn[j]);
            }
        }
    }

    f32x16 accO[4] = {};
    float accLs = 0.0f;
    const float scale = 0.08838834764831845f;

    u16x8 kr[4], vr[4];
    auto sload = [&](int kt) {
        #pragma unroll
        for (int i = 0; i < 4; ++i) {
            int c = i * 256 + tid;
            kr[i] = *reinterpret_cast<const u16x8*>(Kb + (size_t)(kt * 64 + (c >> 4)) * HDIM + (c & 15) * 8);
            vr[i] = *reinterpret_cast<const u16x8*>(Vb + (size_t)(c >> 3) * LL + kt * 64 + (c & 7) * 8);
        }
    };
    auto swrite = [&](int buf) {
        #pragma unroll
        for (int i = 0; i < 4; ++i) {
            int c = i * 256 + tid;
            *reinterpret_cast<u16x8*>(&Kl[buf][c >> 4][(c & 15) * 8]) = kr[i];
            *reinterpret_cast<u16x8*>(&VTl[buf][c >> 3][(c & 7) * 8]) = vr[i];
        }
    };

    sload(0);
    swrite(0);
    __syncthreads();

    for (int kt = 0; kt < LL / 64; ++kt) {
        int cb = kt & 1;
        if (kt + 1 < LL / 64) sload(kt + 1);

        f32x16 s[2] = {};
        __builtin_amdgcn_s_setprio(1);
        #pragma unroll
        for (int kk = 0; kk < 8; ++kk) {
            bf16x8 kf0 = *reinterpret_cast<const bf16x8*>(&Kl[cb][l31][kk * 16 + hl * 8]);
            bf16x8 kf1 = *reinterpret_cast<const bf16x8*>(&Kl[cb][32 + l31][kk * 16 + hl * 8]);
            s[0] = __builtin_amdgcn_mfma_f32_32x32x16_bf16(kf0, qf[kk], s[0], 0, 0, 0);
            s[1] = __builtin_amdgcn_mfma_f32_32x32x16_bf16(kf1, qf[kk], s[1], 0, 0, 0);
        }
        __builtin_amdgcn_s_setprio(0);

        bf16x8 pa[2][2];
        #pragma unroll
        for (int kn = 0; kn < 2; ++kn) {
            float p[16];
            #pragma unroll
            for (int r = 0; r < 16; ++r) {
                p[r] = __expf(s[kn][r] * scale);
                accLs += p[r];
            }
            #pragma unroll
            for (int ksub = 0; ksub < 2; ++ksub) {
                const int bse = ksub * 8;
                u32 a0 = cvtpk(p[bse + 0], p[bse + 1]);
                u32 a1 = cvtpk(p[bse + 2], p[bse + 3]);
                u32 b0 = cvtpk(p[bse + 4], p[bse + 5]);
                u32 b1 = cvtpk(p[bse + 6], p[bse + 7]);
                plswap(a0, b0);
                plswap(a1, b1);
                u32x4 fw; fw[0] = a0; fw[1] = a1; fw[2] = b0; fw[3] = b1;
                pa[kn][ksub] = __builtin_bit_cast(bf16x8, fw);
            }
        }

        __builtin_amdgcn_s_setprio(1);
        #pragma unroll
        for (int kn = 0; kn < 2; ++kn)
            #pragma unroll
            for (int ksub = 0; ksub < 2; ++ksub) {
                #pragma unroll
                for (int dn = 0; dn < 4; ++dn) {
                    bf16x8 vf = *reinterpret_cast<const bf16x8*>(
                        &VTl[cb][dn * 32 + l31][kn * 32 + ksub * 16 + hl * 8]);
                    accO[dn] = __builtin_amdgcn_mfma_f32_32x32x16_bf16(pa[kn][ksub], vf, accO[dn], 0, 0, 0);
                }
            }
        __builtin_amdgcn_s_setprio(0);

        if (kt + 1 < LL / 64) swrite(cb ^ 1);
        __syncthreads();
    }

    float tot = accLs + __shfl_xor(accLs, 32);

    #pragma unroll
    for (int r = 0; r < 16; ++r) {
        int qrow = (r & 3) + 8 * (r >> 2) + 4 * hl;
        float l = __shfl(tot, qrow);
        float inv = 1.0f / l;
        int pos = q0 + qrow;
        #pragma unroll
        for (int dn = 0; dn < 4; ++dn) {
            int d = dn * 32 + l31;
            Y[((size_t)b * LL + pos) * DD + hh * HDIM + d] = f2bf(accO[dn][r] * inv);
        }
    }
}

// ---------------- launch ----------------
extern "C" void kernel_launch(void* const* d_in, const int* in_sizes, int n_in,
                              void* d_out, int out_size, void* d_ws, size_t ws_size,
                              hipStream_t stream) {
    const float* x     = (const float*)d_in[0];
    const float* wqkv  = (const float*)d_in[1];
    const float* wout  = (const float*)d_in[2];
    float* out = (float*)d_out;

    char* ws = (char*)d_ws;
    size_t off = 0;
    auto take = [&](size_t bytes) { char* p = ws + off; off += (bytes + 255) & ~(size_t)255; return p; };
    unsigned short* xb    = (unsigned short*)take((size_t)MM * DD * 2);
    unsigned short* wqkvT = (unsigned short*)take((size_t)DD * NQKV * 2);
    unsigned short* woutT = (unsigned short*)take((size_t)DD * DD * 2);
    unsigned short* Qb    = (unsigned short*)take((size_t)BB * HH * LL * HDIM * 2);
    unsigned short* Kb    = (unsigned short*)take((size_t)BB * HH * LL * HDIM * 2);
    unsigned short* VtB   = (unsigned short*)take((size_t)BB * HH * LL * HDIM * 2);  // [bh][d][L]
    unsigned short* Yb    = (unsigned short*)take((size_t)MM * DD * 2);
    float* ct             = (float*)take((size_t)LL * 64 * 4);
    float* st             = (float*)take((size_t)LL * 64 * 4);
    if (off > ws_size) return;

    k_prep<<<12800, 256, 0, stream>>>(x, xb, wqkv, wqkvT, wout, woutT, ct, st);

    k_gemm384<<<256, 512, 0, stream>>>(xb, wqkvT, Qb, Kb, VtB);
    k_ropek<<<2048, 256, 0, stream>>>(Kb, ct, st);
    k_attn<<<BB * HH * (LL / 128), 256, 0, stream>>>(Qb, Kb, VtB, Yb, ct, st);
    k_gemm2x<<<256, 512, 0, stream>>>(Yb, woutT, out);
}

// Round 15
// 244.537 us; speedup vs baseline: 1.0049x; 1.0049x over previous
//
#include <hip/hip_runtime.h>

typedef __attribute__((ext_vector_type(8))) short bf16x8;
typedef __attribute__((ext_vector_type(8))) unsigned short u16x8;
typedef __attribute__((ext_vector_type(4))) float f32x4;
typedef __attribute__((ext_vector_type(16))) float f32x16;
typedef __attribute__((ext_vector_type(4))) unsigned short u16x4;
typedef __attribute__((ext_vector_type(4))) unsigned int u32x4;
typedef unsigned int u32;

#define BB 2
#define LL 2048
#define DD 2048
#define HH 16
#define HDIM 128
#define MM 4096      // B*L
#define NQKV 6144    // 3*D

__device__ __forceinline__ unsigned short f2bf(float f) {
    unsigned int u = __builtin_bit_cast(unsigned int, f);
    u += 0x7FFFu + ((u >> 16) & 1u);
    return (unsigned short)(u >> 16);
}
__device__ __forceinline__ float bf2f(unsigned short h) {
    unsigned int u = ((unsigned int)h) << 16;
    return __builtin_bit_cast(float, u);
}

__device__ __forceinline__ void gload16(const unsigned short* g, unsigned short* l) {
    __builtin_amdgcn_global_load_lds((const __attribute__((address_space(1))) void*)g,
                                     (__attribute__((address_space(3))) void*)l, 16, 0, 0);
}

// packed f32->bf16 (RNE) and cross-half lane swap, for in-register softmax
__device__ __forceinline__ u32 cvtpk(float lo, float hi) {
    u32 r;
    asm("v_cvt_pk_bf16_f32 %0, %1, %2" : "=v"(r) : "v"(lo), "v"(hi));
    return r;
}
__device__ __forceinline__ void plswap(u32& a, u32& b) {
    asm("v_permlane32_swap_b32 %0, %1" : "+v"(a), "+v"(b));
}

// ============ merged prep: cvt x -> bf16 | transpose-convert wqkv, wout | rope table ============
__global__ __launch_bounds__(256) void k_prep(const float* __restrict__ x, unsigned short* __restrict__ xb,
                                              const float* __restrict__ wqkv, unsigned short* __restrict__ wqkvT,
                                              const float* __restrict__ wout, unsigned short* __restrict__ woutT,
                                              float* __restrict__ ct, float* __restrict__ st) {
    __shared__ unsigned short t[64][72];
    int bid = blockIdx.x;
    int tid = threadIdx.x;
    if (bid < 8192) {
        int i = bid * 256 + tid;
        float4 v = reinterpret_cast<const float4*>(x)[i];
        u16x4 o;
        o[0] = f2bf(v.x); o[1] = f2bf(v.y); o[2] = f2bf(v.z); o[3] = f2bf(v.w);
        reinterpret_cast<u16x4*>(xb)[i] = o;
        return;
    }
    if (bid >= 12288) {
        int idx = (bid - 12288) * 256 + tid;
        int pos = idx >> 6, d = idx & 63;
        float freq = __expf(-(float)d * (9.210340371976184f / 64.0f));
        float ang = (float)pos * freq;
        ct[idx] = cosf(ang);
        st[idx] = sinf(ang);
        return;
    }
    const float* in; unsigned short* out; int K, N, n0, k0;
    if (bid < 11264) {
        int r = bid - 8192;
        in = wqkv; out = wqkvT; K = DD; N = NQKV;
        n0 = (r % 96) * 64; k0 = (r / 96) * 64;
    } else {
        int r = bid - 11264;
        in = wout; out = woutT; K = DD; N = DD;
        n0 = (r & 31) * 64; k0 = (r >> 5) * 64;
    }
    int tr = tid >> 4, tc = tid & 15;
    #pragma unroll
    for (int i = 0; i < 4; ++i) {
        int k = i * 16 + tr;
        float4 v = *reinterpret_cast<const float4*>(in + (size_t)(k0 + k) * N + n0 + tc * 4);
        t[tc * 4 + 0][k] = f2bf(v.x);
        t[tc * 4 + 1][k] = f2bf(v.y);
        t[tc * 4 + 2][k] = f2bf(v.z);
        t[tc * 4 + 3][k] = f2bf(v.w);
    }
    __syncthreads();
    #pragma unroll
    for (int i = 0; i < 4; ++i) {
        int n = i * 16 + tr;
        u16x4 o = *reinterpret_cast<u16x4*>(&t[n][tc * 4]);
        *reinterpret_cast<u16x4*>(out + (size_t)(n0 + n) * K + k0 + tc * 4) = o;
    }
}

// ============ merged: V transpose | RoPE on K (vectorized) ============
__global__ __launch_bounds__(256) void k_tvrope(const unsigned short* __restrict__ V,
                                                unsigned short* __restrict__ Vt,
                                                unsigned short* __restrict__ K,
                                                const float* __restrict__ ct,
                                                const float* __restrict__ st) {
    __shared__ unsigned short t[64][68];
    int bid = blockIdx.x;
    int tid = threadIdx.x;
    if (bid < 2048) {
        int bh = bid >> 6;
        int l0 = ((bid >> 1) & 31) * 64;
        int d0 = (bid & 1) * 64;
        const unsigned short* ib = V + (size_t)bh * LL * HDIM;
        unsigned short* ob = Vt + (size_t)bh * HDIM * LL;
        int tr = tid >> 4, tc = tid & 15;
        #pragma unroll
        for (int i = 0; i < 4; ++i) {
            int l = i * 16 + tr;
            u16x4 v = *reinterpret_cast<const u16x4*>(ib + (size_t)(l0 + l) * HDIM + d0 + tc * 4);
            t[tc * 4 + 0][l] = v[0];
            t[tc * 4 + 1][l] = v[1];
            t[tc * 4 + 2][l] = v[2];
            t[tc * 4 + 3][l] = v[3];
        }
        __syncthreads();
        #pragma unroll
        for (int i = 0; i < 4; ++i) {
            int d = i * 16 + tr;
            u16x4 o = *reinterpret_cast<u16x4*>(&t[d][tc * 4]);
            *reinterpret_cast<u16x4*>(ob + (size_t)(d0 + d) * LL + l0 + tc * 4) = o;
        }
    } else {
        int idx = (bid - 2048) * 256 + tid;
        int d0 = (idx & 7) * 8;
        int pos = (idx >> 3) & (LL - 1);
        int bh = idx >> 14;
        size_t base = ((size_t)bh * LL + pos) * HDIM;
        u16x8 k0 = *reinterpret_cast<const u16x8*>(K + base + d0);
        u16x8 k1 = *reinterpret_cast<const u16x8*>(K + base + 64 + d0);
        u16x8 o0, o1;
        #pragma unroll
        for (int j = 0; j < 8; ++j) {
            float c = ct[pos * 64 + d0 + j], s = st[pos * 64 + d0 + j];
            float a = bf2f(k0[j]), b = bf2f(k1[j]);
            o0[j] = f2bf(a * c - b * s);
            o1[j] = f2bf(b * c + a * s);
        }
        *reinterpret_cast<u16x8*>(K + base + d0) = o0;
        *reinterpret_cast<u16x8*>(K + base + 64 + d0) = o1;
    }
}

// ============ GEMM1 (R8 body, 4 LDS bufs, depth-3 counted vmcnt): 256x384, grid=256 ============
__global__ __launch_bounds__(512, 2) void k_gemm384(const unsigned short* __restrict__ A,
                                                    const unsigned short* __restrict__ Bt,
                                                    unsigned short* __restrict__ outQ,
                                                    unsigned short* __restrict__ outK,
                                                    unsigned short* __restrict__ outV) {
    __shared__ unsigned short sm[4 * 20480];   // 160 KB exactly (1 block/CU)
    const int Kn = DD;
    const int tid = threadIdx.x;
    const int lane = tid & 63, w = tid >> 6;
    const int wm = w >> 2, wn = w & 3;
    const int lrow = lane & 15, lgrp = lane >> 4;
    const int NT = Kn / 32;

    int orig = blockIdx.x;
    int tau = (orig & 7) * 32 + (orig >> 3);
    const int m0 = (tau & 15) * 256, n0 = (tau >> 4) * 384;

    const int srow = lane >> 2, scol = lane & 3;
    const int scolg = ((scol ^ ((srow >> 1) & 3)) * 8);
    const int fcol  = ((lgrp ^ ((lrow >> 1) & 3)) * 8);

    f32x4 acc[8][6] = {};

    auto stageA = [&](int t, int r) {
        unsigned short* dst = sm + (t & 3) * 20480 + (r * 128 + w * 16) * 32;
        gload16(A + (size_t)(m0 + r * 128 + w * 16 + srow) * Kn + t * 32 + scolg, dst);
    };
    auto stageB = [&](int t, int r) {
        unsigned short* dst = sm + (t & 3) * 20480 + 8192 + (r * 128 + w * 16) * 32;
        gload16(Bt + (size_t)(n0 + r * 128 + w * 16 + srow) * Kn + t * 32 + scolg, dst);
    };

    auto body = [&](int t, bool doStage) {
        unsigned short* bufA = sm + (t & 3) * 20480;
        unsigned short* bufB = bufA + 8192;
        bf16x8 af[8], bfr[2];
        #pragma unroll
        for (int f = 0; f < 8; ++f)
            af[f] = *reinterpret_cast<const bf16x8*>(bufA + (wm * 128 + f * 16 + lrow) * 32 + fcol);
        bfr[0] = *reinterpret_cast<const bf16x8*>(bufB + (wn * 96 + 0 * 16 + lrow) * 32 + fcol);
        bfr[1] = *reinterpret_cast<const bf16x8*>(bufB + (wn * 96 + 1 * 16 + lrow) * 32 + fcol);
        if (doStage) { stageA(t + 3, 0); stageA(t + 3, 1); }
        __builtin_amdgcn_s_barrier();
        __builtin_amdgcn_s_setprio(1);
        #pragma unroll
        for (int fm = 0; fm < 8; ++fm)
            #pragma unroll
            for (int j = 0; j < 2; ++j)
                acc[fm][j] = __builtin_amdgcn_mfma_f32_16x16x32_bf16(af[fm], bfr[j], acc[fm][j], 0, 0, 0);
        __builtin_amdgcn_s_setprio(0);
        bfr[0] = *reinterpret_cast<const bf16x8*>(bufB + (wn * 96 + 2 * 16 + lrow) * 32 + fcol);
        bfr[1] = *reinterpret_cast<const bf16x8*>(bufB + (wn * 96 + 3 * 16 + lrow) * 32 + fcol);
        if (doStage) { stageB(t + 3, 0); stageB(t + 3, 1); }
        __builtin_amdgcn_s_barrier();
        __builtin_amdgcn_s_setprio(1);
        #pragma unroll
        for (int fm = 0; fm < 8; ++fm)
            #pragma unroll
            for (int j = 0; j < 2; ++j)
                acc[fm][2 + j] = __builtin_amdgcn_mfma_f32_16x16x32_bf16(af[fm], bfr[j], acc[fm][2 + j], 0, 0, 0);
        __builtin_amdgcn_s_setprio(0);
        bfr[0] = *reinterpret_cast<const bf16x8*>(bufB + (wn * 96 + 4 * 16 + lrow) * 32 + fcol);
        bfr[1] = *reinterpret_cast<const bf16x8*>(bufB + (wn * 96 + 5 * 16 + lrow) * 32 + fcol);
        if (doStage) { stageB(t + 3, 2); }
        __builtin_amdgcn_s_barrier();
        __builtin_amdgcn_s_setprio(1);
        #pragma unroll
        for (int fm = 0; fm < 8; ++fm)
            #pragma unroll
            for (int j = 0; j < 2; ++j)
                acc[fm][4 + j] = __builtin_amdgcn_mfma_f32_16x16x32_bf16(af[fm], bfr[j], acc[fm][4 + j], 0, 0, 0);
        __builtin_amdgcn_s_setprio(0);
    };

    stageA(0, 0); stageA(0, 1); stageB(0, 0); stageB(0, 1); stageB(0, 2);
    stageA(1, 0); stageA(1, 1); stageB(1, 0); stageB(1, 1); stageB(1, 2);
    stageA(2, 0); stageA(2, 1); stageB(2, 0); stageB(2, 1); stageB(2, 2);
    asm volatile("s_waitcnt vmcnt(10)" ::: "memory");
    __builtin_amdgcn_s_barrier();

    for (int t = 0; t < NT - 3; ++t) {
        body(t, true);
        asm volatile("s_waitcnt vmcnt(10)" ::: "memory");
        __builtin_amdgcn_s_barrier();
    }
    body(NT - 3, false);
    asm volatile("s_waitcnt vmcnt(5)" ::: "memory");
    __builtin_amdgcn_s_barrier();
    body(NT - 2, false);
    asm volatile("s_waitcnt vmcnt(0)" ::: "memory");
    __builtin_amdgcn_s_barrier();
    body(NT - 1, false);

    #pragma unroll
    for (int fm = 0; fm < 8; ++fm) {
        int mrow = m0 + wm * 128 + fm * 16 + lgrp * 4;
        #pragma unroll
        for (int fn = 0; fn < 6; ++fn) {
            int ncol = n0 + wn * 96 + fn * 16 + lrow;
            int which = ncol >> 11;
            int rr = ncol & (DD - 1);
            int h = rr >> 7, d = rr & (HDIM - 1);
            unsigned short* dst = (which == 0) ? outQ : ((which == 1) ? outK : outV);
            #pragma unroll
            for (int i = 0; i < 4; ++i) {
                int m = mrow + i;
                int b = m >> 11, pos = m & (LL - 1);
                dst[((size_t)(b * HH + h) * LL + pos) * HDIM + d] = f2bf(acc[fm][fn][i]);
            }
        }
    }
}

// ============ GEMM2: 256x128 tile, 8 waves, grid=256, 3 LDS bufs (2 blocks/CU) ============
__global__ __launch_bounds__(512) void k_gemm2x(const unsigned short* __restrict__ A,
                                                const unsigned short* __restrict__ Bt,
                                                float* __restrict__ outC) {
    __shared__ unsigned short sm[3 * 12288];
    const int Kn = DD, Nn = DD;
    const int tid = threadIdx.x;
    const int lane = tid & 63, w = tid >> 6;
    const int wm = w >> 1, wn = w & 1;
    const int lrow = lane & 15, lgrp = lane >> 4;
    const int NT = Kn / 32;

    int orig = blockIdx.x;
    int tau = (orig & 7) * 32 + (orig >> 3);
    const int m0 = (tau & 15) * 256, n0 = (tau >> 4) * 128;

    const int srow = lane >> 2, scol = lane & 3;
    const int scolg = ((scol ^ ((srow >> 1) & 3)) * 8);
    const int fcol  = ((lgrp ^ ((lrow >> 1) & 3)) * 8);

    f32x4 acc[4][4] = {};

    auto stage = [&](int t) {
        const int kb = t * 32;
        unsigned short* buf = sm + (t % 3) * 12288;
        gload16(A  + (size_t)(m0 + w * 16 + srow) * Kn + kb + scolg,        buf + w * 512);
        gload16(A  + (size_t)(m0 + 128 + w * 16 + srow) * Kn + kb + scolg,  buf + 4096 + w * 512);
        gload16(Bt + (size_t)(n0 + w * 16 + srow) * Kn + kb + scolg,        buf + 8192 + w * 512);
    };

    auto tile_body = [&](int t, bool do_stage) {
        unsigned short* buf = sm + (t % 3) * 12288;
        bf16x8 af[4], bfr[4];
        #pragma unroll
        for (int f = 0; f < 4; ++f)
            af[f] = *reinterpret_cast<const bf16x8*>(buf + (wm * 64 + f * 16 + lrow) * 32 + fcol);
        #pragma unroll
        for (int f = 0; f < 4; ++f)
            bfr[f] = *reinterpret_cast<const bf16x8*>(buf + 8192 + (wn * 64 + f * 16 + lrow) * 32 + fcol);
        if (do_stage) stage(t + 2);
        __builtin_amdgcn_s_barrier();
        __builtin_amdgcn_s_setprio(1);
        #pragma unroll
        for (int fm = 0; fm < 4; ++fm)
            #pragma unroll
            for (int fn = 0; fn < 4; ++fn)
                acc[fm][fn] = __builtin_amdgcn_mfma_f32_16x16x32_bf16(af[fm], bfr[fn], acc[fm][fn], 0, 0, 0);
        __builtin_amdgcn_s_setprio(0);
    };

    stage(0); stage(1);
    asm volatile("s_waitcnt vmcnt(3)" ::: "memory");
    __builtin_amdgcn_s_barrier();

    for (int t = 0; t < NT - 2; ++t) {
        tile_body(t, true);
        asm volatile("s_waitcnt vmcnt(3)" ::: "memory");
        __builtin_amdgcn_s_barrier();
    }
    tile_body(NT - 2, false);
    asm volatile("s_waitcnt vmcnt(0)" ::: "memory");
    __builtin_amdgcn_s_barrier();
    tile_body(NT - 1, false);

    #pragma unroll
    for (int fm = 0; fm < 4; ++fm) {
        int mrow = m0 + wm * 64 + fm * 16 + lgrp * 4;
        #pragma unroll
        for (int fn = 0; fn < 4; ++fn) {
            int ncol = n0 + wn * 64 + fn * 16 + lrow;
            #pragma unroll
            for (int i = 0; i < 4; ++i)
                outC[(size_t)(mrow + i) * (size_t)Nn + ncol] = acc[fm][fn][i];
        }
    }
}

// ============ attention (R9-proven): 4 waves, 32x32 MFMA, swapped QK^T, in-reg softmax, ============
// ============ dbuf, fused Q-RoPE. 180-VGPR live state => 2 waves/SIMD is the max here. ============
__global__ __launch_bounds__(256, 2) void k_attn(const unsigned short* __restrict__ Q,
                                                 const unsigned short* __restrict__ K,
                                                 const unsigned short* __restrict__ Vt,
                                                 unsigned short* __restrict__ Y,
                                                 const float* __restrict__ ct,
                                                 const float* __restrict__ st) {
    __shared__ unsigned short Kl[2][64][136];
    __shared__ unsigned short VTl[2][128][72];
    int tid = threadIdx.x;
    int lane = tid & 63, w = tid >> 6;
    int l31 = lane & 31, hl = lane >> 5;
    int orig = blockIdx.x;
    int id = (orig & 7) * 64 + (orig >> 3);
    int bh = id >> 4, qt = id & 15;
    int b = bh >> 4, hh = bh & 15;
    const unsigned short* Qb = Q  + (size_t)bh * LL * HDIM;
    const unsigned short* Kb = K  + (size_t)bh * LL * HDIM;
    const unsigned short* Vb = Vt + (size_t)bh * HDIM * LL;
    int q0 = qt * 128 + w * 32;

    bf16x8 qf[8];
    #pragma unroll
    for (int kk = 0; kk < 8; ++kk)
        qf[kk] = *reinterpret_cast<const bf16x8*>(
            Qb + (size_t)(q0 + l31) * HDIM + kk * 16 + hl * 8);
    // fused RoPE on Q: pair (d, d+64) = (qf[kk][j], qf[kk+4][j]) for kk<4
    {
        int pos = q0 + l31;
        #pragma unroll
        for (int kk = 0; kk < 4; ++kk) {
            int d0 = kk * 16 + hl * 8;
            float4 c0 = *reinterpret_cast<const float4*>(ct + pos * 64 + d0);
            float4 c1 = *reinterpret_cast<const float4*>(ct + pos * 64 + d0 + 4);
            float4 s0 = *reinterpret_cast<const float4*>(st + pos * 64 + d0);
            float4 s1 = *reinterpret_cast<const float4*>(st + pos * 64 + d0 + 4);
            float cs[8] = {c0.x, c0.y, c0.z, c0.w, c1.x, c1.y, c1.z, c1.w};
            float sn[8] = {s0.x, s0.y, s0.z, s0.w, s1.x, s1.y, s1.z, s1.w};
            #pragma unroll
            for (int j = 0; j < 8; ++j) {
                float a = bf2f((unsigned short)qf[kk][j]);
                float bb2 = bf2f((unsigned short)qf[kk + 4][j]);
                qf[kk][j]     = (short)f2bf(a * cs[j] - bb2 * sn[j]);
                qf[kk + 4][j] = (short)f2bf(bb2 * cs[j] + a * sn[j]);
            }
        }
    }

    f32x16 accO[4] = {};
    float accLs = 0.0f;
    const float scale = 0.08838834764831845f;

    u16x8 kr[4], vr[4];
    auto sload = [&](int kt) {
        #pragma unroll
        for (int i = 0; i < 4; ++i) {
            int c = i * 256 + tid;
            kr[i] = *reinterpret_cast<const u16x8*>(Kb + (size_t)(kt * 64 + (c >> 4)) * HDIM + (c & 15) * 8);
            vr[i] = *reinterpret_cast<const u16x8*>(Vb + (size_t)(c >> 3) * LL + kt * 64 + (c & 7) * 8);
        }
    };
    auto swrite = [&](int buf) {
        #pragma unroll
        for (int i = 0; i < 4; ++i) {
            int c = i * 256 + tid;
            *reinterpret_cast<u16x8*>(&Kl[buf][c >> 4][(c & 15) * 8]) = kr[i];
            *reinterpret_cast<u16x8*>(&VTl[buf][c >> 3][(c & 7) * 8]) = vr[i];
        }
    };

    sload(0);
    swrite(0);
    __syncthreads();

    for (int kt = 0; kt < LL / 64; ++kt) {
        int cb = kt & 1;
        if (kt + 1 < LL / 64) sload(kt + 1);

        f32x16 s[2] = {};
        __builtin_amdgcn_s_setprio(1);
        #pragma unroll
        for (int kk = 0; kk < 8; ++kk) {
            bf16x8 kf0 = *reinterpret_cast<const bf16x8*>(&Kl[cb][l31][kk * 16 + hl * 8]);
            bf16x8 kf1 = *reinterpret_cast<const bf16x8*>(&Kl[cb][32 + l31][kk * 16 + hl * 8]);
            s[0] = __builtin_amdgcn_mfma_f32_32x32x16_bf16(kf0, qf[kk], s[0], 0, 0, 0);
            s[1] = __builtin_amdgcn_mfma_f32_32x32x16_bf16(kf1, qf[kk], s[1], 0, 0, 0);
        }
        __builtin_amdgcn_s_setprio(0);

        bf16x8 pa[2][2];
        #pragma unroll
        for (int kn = 0; kn < 2; ++kn) {
            float p[16];
            #pragma unroll
            for (int r = 0; r < 16; ++r) {
                p[r] = __expf(s[kn][r] * scale);
                accLs += p[r];
            }
            #pragma unroll
            for (int ksub = 0; ksub < 2; ++ksub) {
                const int bse = ksub * 8;
                u32 a0 = cvtpk(p[bse + 0], p[bse + 1]);
                u32 a1 = cvtpk(p[bse + 2], p[bse + 3]);
                u32 b0 = cvtpk(p[bse + 4], p[bse + 5]);
                u32 b1 = cvtpk(p[bse + 6], p[bse + 7]);
                plswap(a0, b0);
                plswap(a1, b1);
                u32x4 fw; fw[0] = a0; fw[1] = a1; fw[2] = b0; fw[3] = b1;
                pa[kn][ksub] = __builtin_bit_cast(bf16x8, fw);
            }
        }

        __builtin_amdgcn_s_setprio(1);
        #pragma unroll
        for (int kn = 0; kn < 2; ++kn)
            #pragma unroll
            for (int ksub = 0; ksub < 2; ++ksub) {
                #pragma unroll
                for (int dn = 0; dn < 4; ++dn) {
                    bf16x8 vf = *reinterpret_cast<const bf16x8*>(
                        &VTl[cb][dn * 32 + l31][kn * 32 + ksub * 16 + hl * 8]);
                    accO[dn] = __builtin_amdgcn_mfma_f32_32x32x16_bf16(pa[kn][ksub], vf, accO[dn], 0, 0, 0);
                }
            }
        __builtin_amdgcn_s_setprio(0);

        if (kt + 1 < LL / 64) swrite(cb ^ 1);
        __syncthreads();
    }

    float tot = accLs + __shfl_xor(accLs, 32);

    #pragma unroll
    for (int r = 0; r < 16; ++r) {
        int qrow = (r & 3) + 8 * (r >> 2) + 4 * hl;
        float l = __shfl(tot, qrow);
        float inv = 1.0f / l;
        int pos = q0 + qrow;
        #pragma unroll
        for (int dn = 0; dn < 4; ++dn) {
            int d = dn * 32 + l31;
            Y[((size_t)b * LL + pos) * DD + hh * HDIM + d] = f2bf(accO[dn][r] * inv);
        }
    }
}

// ---------------- launch ----------------
extern "C" void kernel_launch(void* const* d_in, const int* in_sizes, int n_in,
                              void* d_out, int out_size, void* d_ws, size_t ws_size,
                              hipStream_t stream) {
    const float* x     = (const float*)d_in[0];
    const float* wqkv  = (const float*)d_in[1];
    const float* wout  = (const float*)d_in[2];
    float* out = (float*)d_out;

    char* ws = (char*)d_ws;
    size_t off = 0;
    auto take = [&](size_t bytes) { char* p = ws + off; off += (bytes + 255) & ~(size_t)255; return p; };
    unsigned short* xb    = (unsigned short*)take((size_t)MM * DD * 2);
    unsigned short* wqkvT = (unsigned short*)take((size_t)DD * NQKV * 2);
    unsigned short* woutT = (unsigned short*)take((size_t)DD * DD * 2);
    unsigned short* Qb    = (unsigned short*)take((size_t)BB * HH * LL * HDIM * 2);
    unsigned short* Kb    = (unsigned short*)take((size_t)BB * HH * LL * HDIM * 2);
    unsigned short* Vb    = (unsigned short*)take((size_t)BB * HH * LL * HDIM * 2);
    unsigned short* Yb    = (unsigned short*)take((size_t)MM * DD * 2);
    float* ct             = (float*)take((size_t)LL * 64 * 4);
    float* st             = (float*)take((size_t)LL * 64 * 4);
    if (off > ws_size) return;
    unsigned short* VtB = xb;   // alias: xb dead after gemm1; tvrope runs after gemm1

    k_prep<<<12800, 256, 0, stream>>>(x, xb, wqkv, wqkvT, wout, woutT, ct, st);

    k_gemm384<<<256, 512, 0, stream>>>(xb, wqkvT, Qb, Kb, Vb);
    k_tvrope<<<4096, 256, 0, stream>>>(Vb, VtB, Kb, ct, st);
    k_attn<<<BB * HH * (LL / 128), 256, 0, stream>>>(Qb, Kb, VtB, Yb, ct, st);
    k_gemm2x<<<256, 512, 0, stream>>>(Yb, woutT, out);
}